// Round 1
// baseline (958.842 us; speedup 1.0000x reference)
//
#include <hip/hip_runtime.h>

typedef unsigned int uint;
typedef unsigned short ushort;
typedef _Float16 h2 __attribute__((ext_vector_type(2)));

#define HW 65536
#define W_ 256
#define H_ 256
#define C_ 64

__device__ __forceinline__ h2 u2h(uint u) { union { uint u; h2 h; } x; x.u = u; return x.h; }
__device__ __forceinline__ uint h2u(h2 h) { union { uint u; h2 h; } x; x.h = h; return x.u; }
__device__ __forceinline__ ushort f2hu(float f) { union { ushort u; _Float16 h; } x; x.h = (_Float16)f; return x.u; }
__device__ __forceinline__ float hu2f(ushort u) { union { ushort u; _Float16 h; } x; x.u = u; return (float)x.h; }

__device__ __forceinline__ float fdot2f(h2 a, h2 b, float c) {
#if __has_builtin(__builtin_amdgcn_fdot2)
    return __builtin_amdgcn_fdot2(a, b, c, false);
#else
    return c + (float)a.x * (float)b.x + (float)a.y * (float)b.y;
#endif
}

// ---------------- conv1x1: y[b,o,hw] = sum_c w[o,c] x[b,c,hw] + bias[o] ----------------
__global__ __launch_bounds__(256) void conv1x1_k(const float* __restrict__ x,
                                                 const float* __restrict__ w,
                                                 const float* __restrict__ bias,
                                                 float* __restrict__ y) {
    __shared__ float ws_[4096];
    int tid = threadIdx.x;
    for (int t = tid; t < 4096; t += 256) ws_[t] = w[t];
    __syncthreads();
    int p = blockIdx.x * 256 + tid;          // 0 .. B*HW-1
    int b = p >> 16;
    int hw = p & 65535;
    const float* xp = x + ((size_t)b << 22) + hw;
    float acc[64];
#pragma unroll
    for (int o = 0; o < 64; ++o) acc[o] = 0.0f;
    for (int c = 0; c < 64; ++c) {
        float xv = xp[(size_t)c << 16];
#pragma unroll
        for (int o = 0; o < 64; ++o) acc[o] += ws_[o * 64 + c] * xv;
    }
    float* yp = y + ((size_t)b << 22) + hw;
#pragma unroll
    for (int o = 0; o < 64; ++o) yp[(size_t)o << 16] = acc[o] + bias[o];
}

// ------- depthwise 3x3 (zero pad) + bias, NCHW fp32 -> channels-last f16 -------
// interleave==0: out[(bh*W + w)*64 + c]
// interleave==1: out[bh*W*64 + (w>>1)*128 + c*2 + (w&1)]  (k-pair packed for dot2)
__global__ __launch_bounds__(256) void dw3x3_t_k(const float* __restrict__ x,
                                                 const float* __restrict__ wgt,
                                                 const float* __restrict__ bias,
                                                 ushort* __restrict__ out,
                                                 int interleave) {
    int wt = blockIdx.x;   // 0..3 (w tile of 64)
    int h  = blockIdx.y;   // 0..255
    int b  = blockIdx.z;   // 0..1
    int tid = threadIdx.x;
    int wl = tid & 63, cg = tid >> 6;
    int w0 = wt * 64;
    __shared__ float tile[64][65];

    for (int i = 0; i < 16; ++i) {
        int c = i * 4 + cg;
        const float* wp = wgt + c * 9;
        float acc = bias[c];
        const float* xp = x + (((size_t)b * 64 + c) << 16);
#pragma unroll
        for (int dy = -1; dy <= 1; ++dy) {
            int hh = h + dy;
            if (hh < 0 || hh >= H_) continue;
            const float* row = xp + hh * W_;
#pragma unroll
            for (int dx = -1; dx <= 1; ++dx) {
                int ww = w0 + wl + dx;
                if (ww < 0 || ww >= W_) continue;
                acc += wp[(dy + 1) * 3 + (dx + 1)] * row[ww];
            }
        }
        tile[c][wl] = acc;
    }
    __syncthreads();
    int c2 = tid & 63, jg = tid >> 6;
    size_t base = ((size_t)b * H_ + h) * (size_t)(W_ * 64);
    for (int j = 0; j < 16; ++j) {
        int wcol = j * 4 + jg;
        float v = tile[c2][wcol];
        int wg = w0 + wcol;
        size_t off;
        if (!interleave) off = base + (size_t)wg * 64 + c2;
        else             off = base + (size_t)(wg >> 1) * 128 + c2 * 2 + (wg & 1);
        out[off] = f2hu(v);
    }
}

// ---------------- attention: Out[p,c] = sum_k e_k V[k,c] / sum_k e_k ----------------
// e_k = exp(0.125 * dot64(Qa[p,:], Qb[k,:])).  Qa,Qb plain [k][c] f16; V pair-interleaved.
__global__ __launch_bounds__(256) void att_k(const ushort* __restrict__ Qa,
                                             const ushort* __restrict__ Qb,
                                             const ushort* __restrict__ Vp,
                                             ushort* __restrict__ Out) {
    int bh = blockIdx.x;
    int tid = threadIdx.x;
    __shared__ uint4 sbuf[4096];   // 64 KB: [0,2048) = Qb rows, [2048,4096) = V pairs
    const uint4* qb_g = (const uint4*)(Qb + (size_t)bh * 16384);
    const uint4* v_g  = (const uint4*)(Vp + (size_t)bh * 16384);
    for (int t = tid; t < 2048; t += 256) {
        sbuf[t] = qb_g[t];
        sbuf[t + 2048] = v_g[t];
    }
    // own query row -> 32 packed f16 pairs
    const uint4* qa_g = (const uint4*)(Qa + (size_t)bh * 16384 + (size_t)tid * 64);
    h2 qa2[32];
#pragma unroll
    for (int j = 0; j < 8; ++j) {
        uint4 q = qa_g[j];
        qa2[4 * j + 0] = u2h(q.x); qa2[4 * j + 1] = u2h(q.y);
        qa2[4 * j + 2] = u2h(q.z); qa2[4 * j + 3] = u2h(q.w);
    }
    __syncthreads();
    const uint* qb_s = (const uint*)sbuf;
    const uint* v_s  = (const uint*)(sbuf + 2048);

    float num[64];
#pragma unroll
    for (int c = 0; c < 64; ++c) num[c] = 0.0f;
    float den = 0.0f;

    for (int kk = 0; kk < 128; ++kk) {
        const uint4* r0 = (const uint4*)(qb_s + (kk * 2) * 32);
        const uint4* r1 = r0 + 8;
        float s0 = 0.0f, s1 = 0.0f;
#pragma unroll
        for (int j = 0; j < 8; ++j) {
            uint4 a0 = r0[j];
            uint4 a1 = r1[j];
            s0 = fdot2f(qa2[4 * j + 0], u2h(a0.x), s0);
            s0 = fdot2f(qa2[4 * j + 1], u2h(a0.y), s0);
            s0 = fdot2f(qa2[4 * j + 2], u2h(a0.z), s0);
            s0 = fdot2f(qa2[4 * j + 3], u2h(a0.w), s0);
            s1 = fdot2f(qa2[4 * j + 0], u2h(a1.x), s1);
            s1 = fdot2f(qa2[4 * j + 1], u2h(a1.y), s1);
            s1 = fdot2f(qa2[4 * j + 2], u2h(a1.z), s1);
            s1 = fdot2f(qa2[4 * j + 3], u2h(a1.w), s1);
        }
        float e0 = __expf(s0 * 0.125f);
        float e1 = __expf(s1 * 0.125f);
        den += e0 + e1;
        h2 ep; ep.x = (_Float16)e0; ep.y = (_Float16)e1;
        const uint4* vr = (const uint4*)(v_s + kk * 64);
#pragma unroll
        for (int m = 0; m < 16; ++m) {
            uint4 vv = vr[m];
            num[4 * m + 0] = fdot2f(ep, u2h(vv.x), num[4 * m + 0]);
            num[4 * m + 1] = fdot2f(ep, u2h(vv.y), num[4 * m + 1]);
            num[4 * m + 2] = fdot2f(ep, u2h(vv.z), num[4 * m + 2]);
            num[4 * m + 3] = fdot2f(ep, u2h(vv.w), num[4 * m + 3]);
        }
    }
    float inv = 1.0f / den;
    uint4* op = (uint4*)(Out + (size_t)bh * 16384 + (size_t)tid * 64);
#pragma unroll
    for (int m = 0; m < 8; ++m) {
        uint4 o;
        h2 t0; t0.x = (_Float16)(num[8 * m + 0] * inv); t0.y = (_Float16)(num[8 * m + 1] * inv);
        h2 t1; t1.x = (_Float16)(num[8 * m + 2] * inv); t1.y = (_Float16)(num[8 * m + 3] * inv);
        h2 t2; t2.x = (_Float16)(num[8 * m + 4] * inv); t2.y = (_Float16)(num[8 * m + 5] * inv);
        h2 t3; t3.x = (_Float16)(num[8 * m + 6] * inv); t3.y = (_Float16)(num[8 * m + 7] * inv);
        o.x = h2u(t0); o.y = h2u(t1); o.z = h2u(t2); o.w = h2u(t3);
        op[m] = o;
    }
}

// ------- pattn1 = conv1x1(F_r2l, lp3) + conv1x1(F_l2r, rp3), channels-last f16 in, NCHW fp32 out -------
__global__ __launch_bounds__(256) void p3_k(const ushort* __restrict__ F1,
                                            const ushort* __restrict__ F2,
                                            const float* __restrict__ w1,
                                            const float* __restrict__ b1,
                                            const float* __restrict__ w2,
                                            const float* __restrict__ b2,
                                            float* __restrict__ outp) {
    __shared__ float w1s[4096], w2s[4096];
    __shared__ ushort f1s[64 * 66], f2s[64 * 66];
    int tid = threadIdx.x;
    int pix0 = blockIdx.x * 64;
    const ushort* f1g = F1 + (size_t)pix0 * 64;
    const ushort* f2g = F2 + (size_t)pix0 * 64;
    for (int t = tid; t < 4096; t += 256) {
        w1s[t] = w1[t];
        w2s[t] = w2[t];
        int pp = t >> 6, cc = t & 63;
        f1s[pp * 66 + cc] = f1g[t];
        f2s[pp * 66 + cc] = f2g[t];
    }
    __syncthreads();
    int pix = tid & 63, og = tid >> 6, o0 = og * 16;
    float acc[16];
#pragma unroll
    for (int oo = 0; oo < 16; ++oo) acc[oo] = b1[o0 + oo] + b2[o0 + oo];
    for (int c = 0; c < 64; ++c) {
        float f1v = hu2f(f1s[pix * 66 + c]);
        float f2v = hu2f(f2s[pix * 66 + c]);
#pragma unroll
        for (int oo = 0; oo < 16; ++oo)
            acc[oo] += w1s[(o0 + oo) * 64 + c] * f1v + w2s[(o0 + oo) * 64 + c] * f2v;
    }
    int b = pix0 >> 16;
    int hw = (pix0 & 65535) + pix;
    float* op = outp + ((size_t)b << 22) + hw;
#pragma unroll
    for (int oo = 0; oo < 16; ++oo) op[(size_t)(o0 + oo) << 16] = acc[oo];
}

// ------- pixel attention 7x7 reflect (groups=C, 2 in-ch per group) + double sigmoid + blend -------
__global__ __launch_bounds__(256) void p4_k(const float* __restrict__ x_l,
                                            const float* __restrict__ x_r,
                                            const float* __restrict__ pt,
                                            const float* __restrict__ pw,
                                            const float* __restrict__ pb,
                                            float* __restrict__ out) {
    int h = blockIdx.x & 255;
    int bc = blockIdx.x >> 8;   // b*64 + c
    int c = bc & 63;
    int w = threadIdx.x;
    const float* w0p = pw + c * 98;
    const float* w1p = w0p + 49;
    size_t base = (size_t)bc << 16;

    int wwv[7];
#pragma unroll
    for (int j = 0; j < 7; ++j) {
        int t = w + j - 3;
        wwv[j] = t < 0 ? -t : (t > 255 ? 510 - t : t);
    }
    float acc = pb[c];
    for (int i = 0; i < 7; ++i) {
        int hh = h + i - 3;
        hh = hh < 0 ? -hh : (hh > 255 ? 510 - hh : hh);
        const float* xlr = x_l + base + hh * W_;
        const float* xrr = x_r + base + hh * W_;
        const float* ptr_ = pt + base + hh * W_;
#pragma unroll
        for (int j = 0; j < 7; ++j) {
            int ww = wwv[j];
            acc += w0p[i * 7 + j] * (xlr[ww] + xrr[ww]) + w1p[i * 7 + j] * ptr_[ww];
        }
    }
    float s1 = 1.0f / (1.0f + __expf(-acc));
    float a  = 1.0f / (1.0f + __expf(-s1));
    size_t idx = base + (size_t)h * W_ + w;
    float xl = x_l[idx], xr = x_r[idx];
    out[idx] = xr + a * (xl - xr);
}

extern "C" void kernel_launch(void* const* d_in, const int* in_sizes, int n_in,
                              void* d_out, int out_size, void* d_ws, size_t ws_size,
                              hipStream_t stream) {
    const float* x_l = (const float*)d_in[0];
    const float* x_r = (const float*)d_in[1];
    const float* lp1_w1 = (const float*)d_in[2];
    const float* lp1_b1 = (const float*)d_in[3];
    const float* lp1_w2 = (const float*)d_in[4];
    const float* lp1_b2 = (const float*)d_in[5];
    const float* rp1_w1 = (const float*)d_in[6];
    const float* rp1_b1 = (const float*)d_in[7];
    const float* rp1_w2 = (const float*)d_in[8];
    const float* rp1_b2 = (const float*)d_in[9];
    const float* lp2_w1 = (const float*)d_in[10];
    const float* lp2_b1 = (const float*)d_in[11];
    const float* lp2_w2 = (const float*)d_in[12];
    const float* lp2_b2 = (const float*)d_in[13];
    const float* rp2_w1 = (const float*)d_in[14];
    const float* rp2_b1 = (const float*)d_in[15];
    const float* rp2_w2 = (const float*)d_in[16];
    const float* rp2_b2 = (const float*)d_in[17];
    const float* lp3_w = (const float*)d_in[18];
    const float* lp3_b = (const float*)d_in[19];
    const float* rp3_w = (const float*)d_in[20];
    const float* rp3_b = (const float*)d_in[21];
    const float* pa_w = (const float*)d_in[22];
    const float* pa_b = (const float*)d_in[23];

    const size_t N = (size_t)2 * 64 * 256 * 256;    // 8388608
    char* ws = (char*)d_ws;
    float* tmp = (float*)ws;                        // N fp32 (later reused as pattn1)
    ushort* q_l   = (ushort*)(ws + N * 4);
    ushort* q_r   = q_l + N;
    ushort* v_l   = q_r + N;
    ushort* v_r   = v_l + N;
    ushort* f_r2l = v_r + N;
    ushort* f_l2r = f_r2l + N;

    dim3 blk(256);
    dim3 g_c1(512);            // B*HW/256
    dim3 g_dw(4, 256, 2);      // wtile, h, b
    dim3 g_att(512);           // b*h
    dim3 g_p3(2048);           // B*HW/64
    dim3 g_p4(32768);          // (b*64+c)*256 + h

    // Q_l
    conv1x1_k<<<g_c1, blk, 0, stream>>>(x_l, lp1_w1, lp1_b1, tmp);
    dw3x3_t_k<<<g_dw, blk, 0, stream>>>(tmp, lp1_w2, lp1_b2, q_l, 0);
    // Q_r
    conv1x1_k<<<g_c1, blk, 0, stream>>>(x_r, rp1_w1, rp1_b1, tmp);
    dw3x3_t_k<<<g_dw, blk, 0, stream>>>(tmp, rp1_w2, rp1_b2, q_r, 0);
    // V_l (pair-interleaved)
    conv1x1_k<<<g_c1, blk, 0, stream>>>(x_l, lp2_w1, lp2_b1, tmp);
    dw3x3_t_k<<<g_dw, blk, 0, stream>>>(tmp, lp2_w2, lp2_b2, v_l, 1);
    // V_r (pair-interleaved)
    conv1x1_k<<<g_c1, blk, 0, stream>>>(x_r, rp2_w1, rp2_b1, tmp);
    dw3x3_t_k<<<g_dw, blk, 0, stream>>>(tmp, rp2_w2, rp2_b2, v_r, 1);

    // F_r2l[w,c] = softmax_v(S[w,v]) @ V_r ;  F_l2r[v,c] = softmax_w(S[w,v])^T @ V_l
    att_k<<<g_att, blk, 0, stream>>>(q_l, q_r, v_r, f_r2l);
    att_k<<<g_att, blk, 0, stream>>>(q_r, q_l, v_l, f_l2r);

    // pattn1 = lp3(F_r2l) + rp3(F_l2r)   (tmp reused)
    p3_k<<<g_p3, blk, 0, stream>>>(f_r2l, f_l2r, lp3_w, lp3_b, rp3_w, rp3_b, tmp);

    // out = a*x_l + (1-a)*x_r
    p4_k<<<g_p4, blk, 0, stream>>>(x_l, x_r, tmp, pa_w, pa_b, (float*)d_out);
}

// Round 2
// 889.602 us; speedup vs baseline: 1.0778x; 1.0778x over previous
//
#include <hip/hip_runtime.h>

typedef unsigned int uint;
typedef unsigned short ushort;
typedef _Float16 h2 __attribute__((ext_vector_type(2)));

#define HW 65536
#define W_ 256
#define H_ 256
#define C_ 64

__device__ __forceinline__ h2 u2h(uint u) { union { uint u; h2 h; } x; x.u = u; return x.h; }
__device__ __forceinline__ uint h2u(h2 h) { union { uint u; h2 h; } x; x.h = h; return x.u; }
__device__ __forceinline__ ushort f2hu(float f) { union { ushort u; _Float16 h; } x; x.h = (_Float16)f; return x.u; }
__device__ __forceinline__ float hu2f(ushort u) { union { ushort u; _Float16 h; } x; x.u = u; return (float)x.h; }

__device__ __forceinline__ float fdot2f(h2 a, h2 b, float c) {
#if __has_builtin(__builtin_amdgcn_fdot2)
    return __builtin_amdgcn_fdot2(a, b, c, false);
#else
    return c + (float)a.x * (float)b.x + (float)a.y * (float)b.y;
#endif
}

// ---------------- conv1x1: y[b,o,hw] = sum_c w[o,c] x[b,c,hw] + bias[o], f16 out ----------------
__global__ __launch_bounds__(256) void conv1x1_k(const float* __restrict__ x,
                                                 const float* __restrict__ w,
                                                 const float* __restrict__ bias,
                                                 ushort* __restrict__ y) {
    __shared__ float ws_[4096];
    int tid = threadIdx.x;
    for (int t = tid; t < 4096; t += 256) ws_[t] = w[t];
    __syncthreads();
    int p = blockIdx.x * 256 + tid;          // 0 .. B*HW-1
    int b = p >> 16;
    int hw = p & 65535;
    const float* xp = x + ((size_t)b << 22) + hw;
    float acc[64];
#pragma unroll
    for (int o = 0; o < 64; ++o) acc[o] = 0.0f;
    for (int c = 0; c < 64; ++c) {
        float xv = xp[(size_t)c << 16];
#pragma unroll
        for (int o = 0; o < 64; ++o) acc[o] += ws_[o * 64 + c] * xv;
    }
    ushort* yp = y + ((size_t)b << 22) + hw;
#pragma unroll
    for (int o = 0; o < 64; ++o) yp[(size_t)o << 16] = f2hu(acc[o] + bias[o]);
}

// ------- depthwise 3x3 (zero pad) + bias, NCHW f16 in -> channels-last f16 out -------
// interleave==0: out[(bh*W + w)*64 + c]
// interleave==1: out[bh*W*64 + (w>>1)*128 + c*2 + (w&1)]  (k-pair packed for dot2)
__global__ __launch_bounds__(256) void dw3x3_t_k(const ushort* __restrict__ x,
                                                 const float* __restrict__ wgt,
                                                 const float* __restrict__ bias,
                                                 ushort* __restrict__ out,
                                                 int interleave) {
    int wt = blockIdx.x;   // 0..3 (w tile of 64)
    int h  = blockIdx.y;   // 0..255
    int b  = blockIdx.z;   // 0..1
    int tid = threadIdx.x;
    int wl = tid & 63, cg = tid >> 6;
    int w0 = wt * 64;
    __shared__ float tile[64][65];   // [w][c]

    for (int i = 0; i < 16; ++i) {
        int c = i * 4 + cg;
        const float* wp = wgt + c * 9;
        float acc = bias[c];
        const ushort* xp = x + (((size_t)b * 64 + c) << 16);
#pragma unroll
        for (int dy = -1; dy <= 1; ++dy) {
            int hh = h + dy;
            if (hh < 0 || hh >= H_) continue;
            const ushort* row = xp + hh * W_;
#pragma unroll
            for (int dx = -1; dx <= 1; ++dx) {
                int ww = w0 + wl + dx;
                if (ww < 0 || ww >= W_) continue;
                acc += wp[(dy + 1) * 3 + (dx + 1)] * hu2f(row[ww]);
            }
        }
        tile[wl][c] = acc;
    }
    __syncthreads();
    // block's 4096 output ushorts are contiguous starting at base + w0*64 in BOTH layouts
    size_t base16 = ((size_t)b * H_ + h) * (size_t)(W_ * 64) + (size_t)w0 * 64;
    uint4* og = (uint4*)(out + base16);
#pragma unroll
    for (int u = 0; u < 2; ++u) {
        int i0 = tid * 16 + u * 8;
        ushort vals[8];
#pragma unroll
        for (int k = 0; k < 8; ++k) {
            int i = i0 + k;
            int wl_, c_;
            if (!interleave) { wl_ = i >> 6; c_ = i & 63; }
            else { c_ = (i & 127) >> 1; wl_ = ((i >> 7) << 1) + (i & 1); }
            vals[k] = f2hu(tile[wl_][c_]);
        }
        uint4 o;
        o.x = (uint)vals[0] | ((uint)vals[1] << 16);
        o.y = (uint)vals[2] | ((uint)vals[3] << 16);
        o.z = (uint)vals[4] | ((uint)vals[5] << 16);
        o.w = (uint)vals[6] | ((uint)vals[7] << 16);
        og[tid * 2 + u] = o;
    }
}

// ---------------- attention: Out[p,c] = sum_k e_k V[k,c] / sum_k e_k ----------------
__global__ __launch_bounds__(256) void att_k(const ushort* __restrict__ Qa,
                                             const ushort* __restrict__ Qb,
                                             const ushort* __restrict__ Vp,
                                             ushort* __restrict__ Out) {
    int bh = blockIdx.x;
    int tid = threadIdx.x;
    __shared__ uint4 sbuf[4096];   // 64 KB: [0,2048) = Qb rows, [2048,4096) = V pairs
    const uint4* qb_g = (const uint4*)(Qb + (size_t)bh * 16384);
    const uint4* v_g  = (const uint4*)(Vp + (size_t)bh * 16384);
    for (int t = tid; t < 2048; t += 256) {
        sbuf[t] = qb_g[t];
        sbuf[t + 2048] = v_g[t];
    }
    const uint4* qa_g = (const uint4*)(Qa + (size_t)bh * 16384 + (size_t)tid * 64);
    h2 qa2[32];
#pragma unroll
    for (int j = 0; j < 8; ++j) {
        uint4 q = qa_g[j];
        qa2[4 * j + 0] = u2h(q.x); qa2[4 * j + 1] = u2h(q.y);
        qa2[4 * j + 2] = u2h(q.z); qa2[4 * j + 3] = u2h(q.w);
    }
    __syncthreads();
    const uint* qb_s = (const uint*)sbuf;
    const uint* v_s  = (const uint*)(sbuf + 2048);

    float num[64];
#pragma unroll
    for (int c = 0; c < 64; ++c) num[c] = 0.0f;
    float den = 0.0f;

    for (int kk = 0; kk < 128; ++kk) {
        const uint4* r0 = (const uint4*)(qb_s + (kk * 2) * 32);
        const uint4* r1 = r0 + 8;
        float s0a = 0.0f, s0b = 0.0f, s1a = 0.0f, s1b = 0.0f;
#pragma unroll
        for (int j = 0; j < 8; ++j) {
            uint4 a0 = r0[j];
            uint4 a1 = r1[j];
            s0a = fdot2f(qa2[4 * j + 0], u2h(a0.x), s0a);
            s0b = fdot2f(qa2[4 * j + 1], u2h(a0.y), s0b);
            s0a = fdot2f(qa2[4 * j + 2], u2h(a0.z), s0a);
            s0b = fdot2f(qa2[4 * j + 3], u2h(a0.w), s0b);
            s1a = fdot2f(qa2[4 * j + 0], u2h(a1.x), s1a);
            s1b = fdot2f(qa2[4 * j + 1], u2h(a1.y), s1b);
            s1a = fdot2f(qa2[4 * j + 2], u2h(a1.z), s1a);
            s1b = fdot2f(qa2[4 * j + 3], u2h(a1.w), s1b);
        }
        float e0 = __expf((s0a + s0b) * 0.125f);
        float e1 = __expf((s1a + s1b) * 0.125f);
        den += e0 + e1;
        h2 ep; ep.x = (_Float16)e0; ep.y = (_Float16)e1;
        const uint4* vr = (const uint4*)(v_s + kk * 64);
#pragma unroll
        for (int m = 0; m < 16; ++m) {
            uint4 vv = vr[m];
            num[4 * m + 0] = fdot2f(ep, u2h(vv.x), num[4 * m + 0]);
            num[4 * m + 1] = fdot2f(ep, u2h(vv.y), num[4 * m + 1]);
            num[4 * m + 2] = fdot2f(ep, u2h(vv.z), num[4 * m + 2]);
            num[4 * m + 3] = fdot2f(ep, u2h(vv.w), num[4 * m + 3]);
        }
    }
    float inv = 1.0f / den;
    uint4* op = (uint4*)(Out + (size_t)bh * 16384 + (size_t)tid * 64);
#pragma unroll
    for (int m = 0; m < 8; ++m) {
        uint4 o;
        h2 t0; t0.x = (_Float16)(num[8 * m + 0] * inv); t0.y = (_Float16)(num[8 * m + 1] * inv);
        h2 t1; t1.x = (_Float16)(num[8 * m + 2] * inv); t1.y = (_Float16)(num[8 * m + 3] * inv);
        h2 t2; t2.x = (_Float16)(num[8 * m + 4] * inv); t2.y = (_Float16)(num[8 * m + 5] * inv);
        h2 t3; t3.x = (_Float16)(num[8 * m + 6] * inv); t3.y = (_Float16)(num[8 * m + 7] * inv);
        o.x = h2u(t0); o.y = h2u(t1); o.z = h2u(t2); o.w = h2u(t3);
        op[m] = o;
    }
}

// ------- pattn1 = conv1x1(F_r2l, lp3) + conv1x1(F_l2r, rp3), channels-last f16 in, NCHW f16 out -------
__global__ __launch_bounds__(256) void p3_k(const ushort* __restrict__ F1,
                                            const ushort* __restrict__ F2,
                                            const float* __restrict__ w1,
                                            const float* __restrict__ b1,
                                            const float* __restrict__ w2,
                                            const float* __restrict__ b2,
                                            ushort* __restrict__ outp) {
    __shared__ float w1s[4096], w2s[4096];
    __shared__ ushort f1s[64 * 66], f2s[64 * 66];
    int tid = threadIdx.x;
    int pix0 = blockIdx.x * 64;
    const ushort* f1g = F1 + (size_t)pix0 * 64;
    const ushort* f2g = F2 + (size_t)pix0 * 64;
    for (int t = tid; t < 4096; t += 256) {
        w1s[t] = w1[t];
        w2s[t] = w2[t];
        int pp = t >> 6, cc = t & 63;
        f1s[pp * 66 + cc] = f1g[t];
        f2s[pp * 66 + cc] = f2g[t];
    }
    __syncthreads();
    int pix = tid & 63, og = tid >> 6, o0 = og * 16;
    float acc[16];
#pragma unroll
    for (int oo = 0; oo < 16; ++oo) acc[oo] = b1[o0 + oo] + b2[o0 + oo];
    for (int c = 0; c < 64; ++c) {
        float f1v = hu2f(f1s[pix * 66 + c]);
        float f2v = hu2f(f2s[pix * 66 + c]);
#pragma unroll
        for (int oo = 0; oo < 16; ++oo)
            acc[oo] += w1s[(o0 + oo) * 64 + c] * f1v + w2s[(o0 + oo) * 64 + c] * f2v;
    }
    int b = pix0 >> 16;
    int hw = (pix0 & 65535) + pix;
    ushort* op = outp + ((size_t)b << 22) + hw;
#pragma unroll
    for (int oo = 0; oo < 16; ++oo) op[(size_t)(o0 + oo) << 16] = f2hu(acc[oo]);
}

// ------- pixel attention 7x7 reflect + double sigmoid + blend, LDS-tiled -------
// one block per (b,c, 16-row tile); thread = column; ring of 7 accumulators slides down rows.
__global__ __launch_bounds__(256) void p4_k(const float* __restrict__ x_l,
                                            const float* __restrict__ x_r,
                                            const ushort* __restrict__ pt,
                                            const float* __restrict__ pw,
                                            const float* __restrict__ pb,
                                            float* __restrict__ out) {
    __shared__ float s_t[22 * 264];
    __shared__ float p_t[22 * 264];
    int tid = threadIdx.x;
    int tile = blockIdx.x & 15;
    int bc = blockIdx.x >> 4;        // b*64 + c
    int c = bc & 63;
    int h0 = tile << 4;
    size_t cbase = (size_t)bc << 16;

    // stage 22 reflect-padded rows of s = x_l + x_r and of pattn1
    for (int r = 0; r < 22; ++r) {
        int hh = h0 + r - 3;
        hh = hh < 0 ? -hh : (hh > 255 ? 510 - hh : hh);
        size_t rb = cbase + (size_t)hh * 256;
        s_t[r * 264 + 3 + tid] = x_l[rb + tid] + x_r[rb + tid];
        p_t[r * 264 + 3 + tid] = hu2f(pt[rb + tid]);
    }
    if (tid < 132) {
        int r = tid / 6, d6 = tid % 6;
        int d   = d6 < 3 ? d6 : 256 + d6;       // dest col in padded tile
        int src = d6 < 3 ? (3 - d6) : (257 - d6); // reflected source col
        int hh = h0 + r - 3;
        hh = hh < 0 ? -hh : (hh > 255 ? 510 - hh : hh);
        size_t rb = cbase + (size_t)hh * 256;
        s_t[r * 264 + d] = x_l[rb + src] + x_r[rb + src];
        p_t[r * 264 + d] = hu2f(pt[rb + src]);
    }
    __syncthreads();

    const float* wAp = pw + c * 98;   // weights vs s
    const float* wBp = wAp + 49;      // weights vs pattn1
    float bias = pb[c];
    int w = tid;
    float a0 = bias, a1 = bias, a2 = bias, a3 = bias, a4 = bias, a5 = bias, a6 = bias;
    size_t obase = cbase + (size_t)h0 * 256 + w;

#pragma unroll
    for (int r = 0; r < 22; ++r) {
#pragma unroll
        for (int j = 0; j < 7; ++j) {
            float sv = s_t[r * 264 + w + j];
            float pv = p_t[r * 264 + w + j];
            a0 += wAp[42 + j] * sv + wBp[42 + j] * pv;  // i=6 (oldest)
            a1 += wAp[35 + j] * sv + wBp[35 + j] * pv;
            a2 += wAp[28 + j] * sv + wBp[28 + j] * pv;
            a3 += wAp[21 + j] * sv + wBp[21 + j] * pv;
            a4 += wAp[14 + j] * sv + wBp[14 + j] * pv;
            a5 += wAp[ 7 + j] * sv + wBp[ 7 + j] * pv;
            a6 += wAp[     j] * sv + wBp[     j] * pv;  // i=0 (newest)
        }
        if (r >= 6) {
            int o = r - 6;
            size_t idx = obase + (size_t)o * 256;
            float xl = x_l[idx], xr = x_r[idx];
            float s1 = 1.0f / (1.0f + __expf(-a0));
            float a  = 1.0f / (1.0f + __expf(-s1));
            out[idx] = xr + a * (xl - xr);
        }
        a0 = a1; a1 = a2; a2 = a3; a3 = a4; a4 = a5; a5 = a6; a6 = bias;
    }
}

extern "C" void kernel_launch(void* const* d_in, const int* in_sizes, int n_in,
                              void* d_out, int out_size, void* d_ws, size_t ws_size,
                              hipStream_t stream) {
    const float* x_l = (const float*)d_in[0];
    const float* x_r = (const float*)d_in[1];
    const float* lp1_w1 = (const float*)d_in[2];
    const float* lp1_b1 = (const float*)d_in[3];
    const float* lp1_w2 = (const float*)d_in[4];
    const float* lp1_b2 = (const float*)d_in[5];
    const float* rp1_w1 = (const float*)d_in[6];
    const float* rp1_b1 = (const float*)d_in[7];
    const float* rp1_w2 = (const float*)d_in[8];
    const float* rp1_b2 = (const float*)d_in[9];
    const float* lp2_w1 = (const float*)d_in[10];
    const float* lp2_b1 = (const float*)d_in[11];
    const float* lp2_w2 = (const float*)d_in[12];
    const float* lp2_b2 = (const float*)d_in[13];
    const float* rp2_w1 = (const float*)d_in[14];
    const float* rp2_b1 = (const float*)d_in[15];
    const float* rp2_w2 = (const float*)d_in[16];
    const float* rp2_b2 = (const float*)d_in[17];
    const float* lp3_w = (const float*)d_in[18];
    const float* lp3_b = (const float*)d_in[19];
    const float* rp3_w = (const float*)d_in[20];
    const float* rp3_b = (const float*)d_in[21];
    const float* pa_w = (const float*)d_in[22];
    const float* pa_b = (const float*)d_in[23];

    const size_t N = (size_t)2 * 64 * 256 * 256;    // 8388608
    char* ws = (char*)d_ws;
    ushort* tmp = (ushort*)ws;                      // f16 tmp (conv1x1 out, later pattn1)
    ushort* q_l   = (ushort*)(ws + N * 4);
    ushort* q_r   = q_l + N;
    ushort* v_l   = q_r + N;
    ushort* v_r   = v_l + N;
    ushort* f_r2l = v_r + N;
    ushort* f_l2r = f_r2l + N;

    dim3 blk(256);
    dim3 g_c1(512);            // B*HW/256
    dim3 g_dw(4, 256, 2);      // wtile, h, b
    dim3 g_att(512);           // b*h
    dim3 g_p3(2048);           // B*HW/64
    dim3 g_p4(2048);           // (b*64+c)*16 + htile

    conv1x1_k<<<g_c1, blk, 0, stream>>>(x_l, lp1_w1, lp1_b1, tmp);
    dw3x3_t_k<<<g_dw, blk, 0, stream>>>(tmp, lp1_w2, lp1_b2, q_l, 0);
    conv1x1_k<<<g_c1, blk, 0, stream>>>(x_r, rp1_w1, rp1_b1, tmp);
    dw3x3_t_k<<<g_dw, blk, 0, stream>>>(tmp, rp1_w2, rp1_b2, q_r, 0);
    conv1x1_k<<<g_c1, blk, 0, stream>>>(x_l, lp2_w1, lp2_b1, tmp);
    dw3x3_t_k<<<g_dw, blk, 0, stream>>>(tmp, lp2_w2, lp2_b2, v_l, 1);
    conv1x1_k<<<g_c1, blk, 0, stream>>>(x_r, rp2_w1, rp2_b1, tmp);
    dw3x3_t_k<<<g_dw, blk, 0, stream>>>(tmp, rp2_w2, rp2_b2, v_r, 1);

    att_k<<<g_att, blk, 0, stream>>>(q_l, q_r, v_r, f_r2l);
    att_k<<<g_att, blk, 0, stream>>>(q_r, q_l, v_l, f_l2r);

    p3_k<<<g_p3, blk, 0, stream>>>(f_r2l, f_l2r, lp3_w, lp3_b, rp3_w, rp3_b, tmp);

    p4_k<<<g_p4, blk, 0, stream>>>(x_l, x_r, tmp, pa_w, pa_b, (float*)d_out);
}

// Round 3
// 687.496 us; speedup vs baseline: 1.3947x; 1.2940x over previous
//
#include <hip/hip_runtime.h>

typedef unsigned int uint;
typedef unsigned short ushort;
typedef _Float16 h2 __attribute__((ext_vector_type(2)));
typedef _Float16 f16x8 __attribute__((ext_vector_type(8)));
typedef float f32x4 __attribute__((ext_vector_type(4)));

#define HW 65536
#define W_ 256
#define H_ 256
#define C_ 64

__device__ __forceinline__ ushort f2hu(float f) { union { ushort u; _Float16 h; } x; x.h = (_Float16)f; return x.u; }
__device__ __forceinline__ float hu2f(ushort u) { union { ushort u; _Float16 h; } x; x.u = u; return (float)x.h; }

#define MFMA16(a, b, c) __builtin_amdgcn_mfma_f32_16x16x32_f16((a), (b), (c), 0, 0, 0)

// ---------------- weight transpose: wT[m][c*64+o] = w_m[o*64+c] ----------------
__global__ __launch_bounds__(256) void wtrans_k(const float* __restrict__ a0, const float* __restrict__ a1,
                                                const float* __restrict__ a2, const float* __restrict__ a3,
                                                const float* __restrict__ a4, const float* __restrict__ a5,
                                                float* __restrict__ dst) {
    int m = blockIdx.x;
    const float* src = m == 0 ? a0 : m == 1 ? a1 : m == 2 ? a2 : m == 3 ? a3 : m == 4 ? a4 : a5;
    float* d = dst + m * 4096;
    for (int i = threadIdx.x; i < 4096; i += 256) {
        int o = i >> 6, c = i & 63;
        d[c * 64 + o] = src[i];
    }
}

// ---------------- conv1x1: y[b,o,hw] = sum_c wT[c][o] x[b,c,hw] + bias[o], f16 out ----------------
// weights read with wave-uniform indices -> scalar (s_load) path, no LDS.
__global__ __launch_bounds__(256) void conv1x1_k(const float* __restrict__ x,
                                                 const float* __restrict__ wt,
                                                 const float* __restrict__ bias,
                                                 ushort* __restrict__ y) {
    int tid = threadIdx.x;
    int p = blockIdx.x * 256 + tid;          // 0 .. B*HW-1
    int b = p >> 16;
    int hw = p & 65535;
    const float* xp = x + ((size_t)b << 22) + hw;
    float acc[64];
#pragma unroll
    for (int o = 0; o < 64; ++o) acc[o] = bias[o];
    for (int c = 0; c < 64; ++c) {
        float xv = xp[(size_t)c << 16];
        const float* wc = wt + (c << 6);
#pragma unroll
        for (int o = 0; o < 64; ++o) acc[o] = fmaf(wc[o], xv, acc[o]);
    }
    ushort* yp = y + ((size_t)b << 22) + hw;
#pragma unroll
    for (int o = 0; o < 64; ++o) yp[(size_t)o << 16] = f2hu(acc[o]);
}

// ------- depthwise 3x3 (zero pad) + bias, NCHW f16 in -> f16 out -------
// mode==0: out[bh*16384 + w*64 + c]   (channels-last, for Q)
// mode==2: out[bh*16384 + c*256 + w]  (plane layout, for V)
__global__ __launch_bounds__(256) void dw3x3_t_k(const ushort* __restrict__ x,
                                                 const float* __restrict__ wgt,
                                                 const float* __restrict__ bias,
                                                 ushort* __restrict__ out,
                                                 int mode) {
    int wt = blockIdx.x;   // 0..3 (w tile of 64)
    int h  = blockIdx.y;   // 0..255
    int b  = blockIdx.z;   // 0..1
    int tid = threadIdx.x;
    int wl = tid & 63, cg = tid >> 6;
    int w0 = wt * 64;
    __shared__ float tile[64][65];   // [w][c]

    for (int i = 0; i < 16; ++i) {
        int c = i * 4 + cg;
        const float* wp = wgt + c * 9;
        float acc = bias[c];
        const ushort* xp = x + (((size_t)b * 64 + c) << 16);
#pragma unroll
        for (int dy = -1; dy <= 1; ++dy) {
            int hh = h + dy;
            if (hh < 0 || hh >= H_) continue;
            const ushort* row = xp + hh * W_;
#pragma unroll
            for (int dx = -1; dx <= 1; ++dx) {
                int ww = w0 + wl + dx;
                if (ww < 0 || ww >= W_) continue;
                acc += wp[(dy + 1) * 3 + (dx + 1)] * hu2f(row[ww]);
            }
        }
        tile[wl][c] = acc;
    }
    __syncthreads();
    size_t bh16 = ((size_t)b * H_ + h) * (size_t)(W_ * 64);
    if (mode == 0) {
        // contiguous 4096 u16 starting at bh16 + w0*64, element i -> (w=i>>6, c=i&63)
        uint4* og = (uint4*)(out + bh16 + (size_t)w0 * 64);
#pragma unroll
        for (int u = 0; u < 2; ++u) {
            int i0 = (u * 256 + tid) * 8;
            ushort vals[8];
#pragma unroll
            for (int k = 0; k < 8; ++k) {
                int i = i0 + k;
                vals[k] = f2hu(tile[i >> 6][i & 63]);
            }
            uint4 o;
            o.x = (uint)vals[0] | ((uint)vals[1] << 16);
            o.y = (uint)vals[2] | ((uint)vals[3] << 16);
            o.z = (uint)vals[4] | ((uint)vals[5] << 16);
            o.w = (uint)vals[6] | ((uint)vals[7] << 16);
            og[u * 256 + tid] = o;
        }
    } else {
        // plane layout: 64 rows (c), each 64 u16 at out[bh16 + c*256 + w0 ...]
#pragma unroll
        for (int u = 0; u < 2; ++u) {
            int i = u * 256 + tid;           // 0..511 uint4 index
            int c = i >> 3, wch = i & 7;
            ushort vals[8];
#pragma unroll
            for (int k = 0; k < 8; ++k) vals[k] = f2hu(tile[wch * 8 + k][c]);
            uint4 o;
            o.x = (uint)vals[0] | ((uint)vals[1] << 16);
            o.y = (uint)vals[2] | ((uint)vals[3] << 16);
            o.z = (uint)vals[4] | ((uint)vals[5] << 16);
            o.w = (uint)vals[6] | ((uint)vals[7] << 16);
            *(uint4*)(out + bh16 + (size_t)c * 256 + w0 + wch * 8) = o;
        }
    }
}

// ---------------- combined MFMA attention ----------------
// Per block (bh): E = exp(0.125 * Ql Qr^T)  (256x256, in 4 k-tiles of 64)
//   F_r2l[p][c] = (E @ Vr)[p][c] / rowsum(E)[p]
//   F_l2r[v][c] = (E^T @ Vl)[v][c] / colsum(E)[v]
// Ql,Qr: [bh][pos][c] f16;  Vl,Vr: [bh][c][pos] f16 (plane).
// MFMA f16 16x16x32 layouts: A[m=lane&15][k=quad*8+j], B[k=quad*8+j][n=lane&15],
// C/D: row=quad*4+reg, col=lane&15.  den via B=ones keeps den in C-layout rows
// -> normalization is lane-local.
__global__ __launch_bounds__(256, 2) void att2_k(const ushort* __restrict__ Ql,
                                                 const ushort* __restrict__ Qr,
                                                 const ushort* __restrict__ Vl,
                                                 const ushort* __restrict__ Vr,
                                                 ushort* __restrict__ Fr2l,
                                                 ushort* __restrict__ Fl2r) {
    int bh = blockIdx.x;
    int tid = threadIdx.x;
    int wv = tid >> 6, lane = tid & 63;
    int l15 = lane & 15, quad = lane >> 4;
    __shared__ ushort sE[256 * 72];    // E row-major [p][kcol], stride 72
    __shared__ ushort sEt[64 * 264];   // E col-major [kcol][p], stride 264

    const ushort* qlb = Ql + (size_t)bh * 16384;
    const ushort* qrb = Qr + (size_t)bh * 16384;
    const ushort* vlb = Vl + (size_t)bh * 16384;
    const ushort* vrb = Vr + (size_t)bh * 16384;
    int p0 = wv * 64;                  // wave's p-range for GEMM1/2
    int c0 = wv * 16;                  // wave's c-range for GEMM3

    // preload Ql A-frags (loop-invariant): aQ[mt][kc]
    f16x8 aQ[4][2];
#pragma unroll
    for (int mt = 0; mt < 4; ++mt)
#pragma unroll
        for (int kc = 0; kc < 2; ++kc)
            aQ[mt][kc] = *(const f16x8*)(qlb + (p0 + mt * 16 + l15) * 64 + kc * 32 + quad * 8);

    f16x8 onesf;
#pragma unroll
    for (int i = 0; i < 8; ++i) onesf[i] = (_Float16)1.0f;

    f32x4 num1[4][4];
    f32x4 den[4];
#pragma unroll
    for (int mt = 0; mt < 4; ++mt) {
        den[mt] = (f32x4)(0.0f);
#pragma unroll
        for (int nt = 0; nt < 4; ++nt) num1[mt][nt] = (f32x4)(0.0f);
    }

    for (int kt = 0; kt < 4; ++kt) {
        int k0 = kt * 64;
        // ---- GEMM1: S[p-range][64 kcol] ----
        f32x4 S[4][4];
#pragma unroll
        for (int nt = 0; nt < 4; ++nt) {
            f16x8 bQ[2];
#pragma unroll
            for (int kc = 0; kc < 2; ++kc)
                bQ[kc] = *(const f16x8*)(qrb + (k0 + nt * 16 + l15) * 64 + kc * 32 + quad * 8);
#pragma unroll
            for (int mt = 0; mt < 4; ++mt) {
                f32x4 s = (f32x4)(0.0f);
                s = MFMA16(aQ[mt][0], bQ[0], s);
                s = MFMA16(aQ[mt][1], bQ[1], s);
                S[mt][nt] = s;
            }
        }
        // exp in place
#pragma unroll
        for (int mt = 0; mt < 4; ++mt)
#pragma unroll
            for (int nt = 0; nt < 4; ++nt)
#pragma unroll
                for (int r = 0; r < 4; ++r)
                    S[mt][nt][r] = __expf(S[mt][nt][r] * 0.125f);

        __syncthreads();   // previous tile's sE/sEt reads done
        // write E row-major
#pragma unroll
        for (int mt = 0; mt < 4; ++mt)
#pragma unroll
            for (int nt = 0; nt < 4; ++nt)
#pragma unroll
                for (int r = 0; r < 4; ++r)
                    sE[(p0 + mt * 16 + quad * 4 + r) * 72 + nt * 16 + l15] = f2hu(S[mt][nt][r]);
        // write E col-major (pairs along p)
#pragma unroll
        for (int mt = 0; mt < 4; ++mt)
#pragma unroll
            for (int nt = 0; nt < 4; ++nt)
#pragma unroll
            for (int pr = 0; pr < 4; pr += 2) {
                h2 hh;
                hh.x = (_Float16)S[mt][nt][pr];
                hh.y = (_Float16)S[mt][nt][pr + 1];
                *(h2*)&sEt[(nt * 16 + l15) * 264 + p0 + mt * 16 + quad * 4 + pr] = hh;
            }
        __syncthreads();

        // ---- A-frags of E (row-major) ----
        f16x8 aE[4][2];
#pragma unroll
        for (int mt = 0; mt < 4; ++mt)
#pragma unroll
            for (int kc = 0; kc < 2; ++kc)
                aE[mt][kc] = *(const f16x8*)&sE[(p0 + mt * 16 + l15) * 72 + kc * 32 + quad * 8];
        // den += E @ ones
#pragma unroll
        for (int mt = 0; mt < 4; ++mt) {
            den[mt] = MFMA16(aE[mt][0], onesf, den[mt]);
            den[mt] = MFMA16(aE[mt][1], onesf, den[mt]);
        }
        // ---- GEMM2: num1 += E @ Vr_tile ----
#pragma unroll
        for (int nt = 0; nt < 4; ++nt) {
            f16x8 bV[2];
#pragma unroll
            for (int kc = 0; kc < 2; ++kc)
                bV[kc] = *(const f16x8*)(vrb + (nt * 16 + l15) * 256 + k0 + kc * 32 + quad * 8);
#pragma unroll
            for (int mt = 0; mt < 4; ++mt) {
                num1[mt][nt] = MFMA16(aE[mt][0], bV[0], num1[mt][nt]);
                num1[mt][nt] = MFMA16(aE[mt][1], bV[1], num1[mt][nt]);
            }
        }
        // ---- GEMM3: num2 = E^T @ Vl (N split by wave), den2 = E^T @ ones ----
        f32x4 num2[4], den2[4];
#pragma unroll
        for (int mt = 0; mt < 4; ++mt) { num2[mt] = (f32x4)(0.0f); den2[mt] = (f32x4)(0.0f); }
        for (int pc = 0; pc < 8; ++pc) {
            f16x8 bL = *(const f16x8*)(vlb + (c0 + l15) * 256 + pc * 32 + quad * 8);
#pragma unroll
            for (int mt = 0; mt < 4; ++mt) {
                f16x8 aT = *(const f16x8*)&sEt[(mt * 16 + l15) * 264 + pc * 32 + quad * 8];
                num2[mt] = MFMA16(aT, bL, num2[mt]);
                den2[mt] = MFMA16(aT, onesf, den2[mt]);
            }
        }
        // write F_l2r rows of this k-tile
#pragma unroll
        for (int mt = 0; mt < 4; ++mt)
#pragma unroll
            for (int r = 0; r < 4; ++r) {
                float v = num2[mt][r] * (1.0f / den2[mt][r]);
                Fl2r[(size_t)bh * 16384 + (k0 + mt * 16 + quad * 4 + r) * 64 + c0 + l15] = f2hu(v);
            }
    }
    // epilogue: F_r2l
#pragma unroll
    for (int mt = 0; mt < 4; ++mt)
#pragma unroll
        for (int r = 0; r < 4; ++r) {
            float inv = 1.0f / den[mt][r];
#pragma unroll
            for (int nt = 0; nt < 4; ++nt) {
                float v = num1[mt][nt][r] * inv;
                Fr2l[(size_t)bh * 16384 + (p0 + mt * 16 + quad * 4 + r) * 64 + nt * 16 + l15] = f2hu(v);
            }
        }
}

// ------- pattn1 = conv1x1(F_r2l, lp3) + conv1x1(F_l2r, rp3), channels-last f16 in, NCHW f16 out -------
// weights pre-transposed (wT[c][o]), read scalar.
__global__ __launch_bounds__(256) void p3_k(const ushort* __restrict__ F1,
                                            const ushort* __restrict__ F2,
                                            const float* __restrict__ wt1,
                                            const float* __restrict__ b1,
                                            const float* __restrict__ wt2,
                                            const float* __restrict__ b2,
                                            ushort* __restrict__ outp) {
    __shared__ ushort f1s[64 * 66], f2s[64 * 66];
    int tid = threadIdx.x;
    int pix0 = blockIdx.x * 64;
    const ushort* f1g = F1 + (size_t)pix0 * 64;
    const ushort* f2g = F2 + (size_t)pix0 * 64;
    for (int t = tid; t < 4096; t += 256) {
        int pp = t >> 6, cc = t & 63;
        f1s[pp * 66 + cc] = f1g[t];
        f2s[pp * 66 + cc] = f2g[t];
    }
    __syncthreads();
    int pix = tid & 63, og = tid >> 6, o0 = og * 16;
    float acc[16];
#pragma unroll
    for (int oo = 0; oo < 16; ++oo) acc[oo] = b1[o0 + oo] + b2[o0 + oo];
    for (int c = 0; c < 64; ++c) {
        float f1v = hu2f(f1s[pix * 66 + c]);
        float f2v = hu2f(f2s[pix * 66 + c]);
        const float* w1c = wt1 + (c << 6) + o0;
        const float* w2c = wt2 + (c << 6) + o0;
#pragma unroll
        for (int oo = 0; oo < 16; ++oo)
            acc[oo] += w1c[oo] * f1v + w2c[oo] * f2v;
    }
    int b = pix0 >> 16;
    int hw = (pix0 & 65535) + pix;
    ushort* op = outp + ((size_t)b << 22) + hw;
#pragma unroll
    for (int oo = 0; oo < 16; ++oo) op[(size_t)(o0 + oo) << 16] = f2hu(acc[oo]);
}

// ------- pixel attention 7x7 reflect + double sigmoid + blend, LDS-tiled -------
__global__ __launch_bounds__(256) void p4_k(const float* __restrict__ x_l,
                                            const float* __restrict__ x_r,
                                            const ushort* __restrict__ pt,
                                            const float* __restrict__ pw,
                                            const float* __restrict__ pb,
                                            float* __restrict__ out) {
    __shared__ float s_t[22 * 264];
    __shared__ float p_t[22 * 264];
    int tid = threadIdx.x;
    int tile = blockIdx.x & 15;
    int bc = blockIdx.x >> 4;        // b*64 + c
    int c = bc & 63;
    int h0 = tile << 4;
    size_t cbase = (size_t)bc << 16;

    for (int r = 0; r < 22; ++r) {
        int hh = h0 + r - 3;
        hh = hh < 0 ? -hh : (hh > 255 ? 510 - hh : hh);
        size_t rb = cbase + (size_t)hh * 256;
        s_t[r * 264 + 3 + tid] = x_l[rb + tid] + x_r[rb + tid];
        p_t[r * 264 + 3 + tid] = hu2f(pt[rb + tid]);
    }
    if (tid < 132) {
        int r = tid / 6, d6 = tid % 6;
        int d   = d6 < 3 ? d6 : 256 + d6;
        int src = d6 < 3 ? (3 - d6) : (257 - d6);
        int hh = h0 + r - 3;
        hh = hh < 0 ? -hh : (hh > 255 ? 510 - hh : hh);
        size_t rb = cbase + (size_t)hh * 256;
        s_t[r * 264 + d] = x_l[rb + src] + x_r[rb + src];
        p_t[r * 264 + d] = hu2f(pt[rb + src]);
    }
    __syncthreads();

    const float* wAp = pw + c * 98;
    const float* wBp = wAp + 49;
    float bias = pb[c];
    int w = tid;
    float a0 = bias, a1 = bias, a2 = bias, a3 = bias, a4 = bias, a5 = bias, a6 = bias;
    size_t obase = cbase + (size_t)h0 * 256 + w;

#pragma unroll
    for (int r = 0; r < 22; ++r) {
#pragma unroll
        for (int j = 0; j < 7; ++j) {
            float sv = s_t[r * 264 + w + j];
            float pv = p_t[r * 264 + w + j];
            a0 += wAp[42 + j] * sv + wBp[42 + j] * pv;
            a1 += wAp[35 + j] * sv + wBp[35 + j] * pv;
            a2 += wAp[28 + j] * sv + wBp[28 + j] * pv;
            a3 += wAp[21 + j] * sv + wBp[21 + j] * pv;
            a4 += wAp[14 + j] * sv + wBp[14 + j] * pv;
            a5 += wAp[ 7 + j] * sv + wBp[ 7 + j] * pv;
            a6 += wAp[     j] * sv + wBp[     j] * pv;
        }
        if (r >= 6) {
            int o = r - 6;
            size_t idx = obase + (size_t)o * 256;
            float xl = x_l[idx], xr = x_r[idx];
            float s1 = 1.0f / (1.0f + __expf(-a0));
            float a  = 1.0f / (1.0f + __expf(-s1));
            out[idx] = xr + a * (xl - xr);
        }
        a0 = a1; a1 = a2; a2 = a3; a3 = a4; a4 = a5; a5 = a6; a6 = bias;
    }
}

extern "C" void kernel_launch(void* const* d_in, const int* in_sizes, int n_in,
                              void* d_out, int out_size, void* d_ws, size_t ws_size,
                              hipStream_t stream) {
    const float* x_l = (const float*)d_in[0];
    const float* x_r = (const float*)d_in[1];
    const float* lp1_w1 = (const float*)d_in[2];
    const float* lp1_b1 = (const float*)d_in[3];
    const float* lp1_w2 = (const float*)d_in[4];
    const float* lp1_b2 = (const float*)d_in[5];
    const float* rp1_w1 = (const float*)d_in[6];
    const float* rp1_b1 = (const float*)d_in[7];
    const float* rp1_w2 = (const float*)d_in[8];
    const float* rp1_b2 = (const float*)d_in[9];
    const float* lp2_w1 = (const float*)d_in[10];
    const float* lp2_b1 = (const float*)d_in[11];
    const float* lp2_w2 = (const float*)d_in[12];
    const float* lp2_b2 = (const float*)d_in[13];
    const float* rp2_w1 = (const float*)d_in[14];
    const float* rp2_b1 = (const float*)d_in[15];
    const float* rp2_w2 = (const float*)d_in[16];
    const float* rp2_b2 = (const float*)d_in[17];
    const float* lp3_w = (const float*)d_in[18];
    const float* lp3_b = (const float*)d_in[19];
    const float* rp3_w = (const float*)d_in[20];
    const float* rp3_b = (const float*)d_in[21];
    const float* pa_w = (const float*)d_in[22];
    const float* pa_b = (const float*)d_in[23];

    const size_t N = (size_t)2 * 64 * 256 * 256;    // 8388608
    char* ws = (char*)d_ws;
    ushort* tmp = (ushort*)ws;                      // N u16 (conv1x1 out, later pattn1)
    float* wT   = (float*)(ws + N * 2);             // 6 * 4096 transposed weights
    ushort* q_l   = (ushort*)(ws + N * 4);
    ushort* q_r   = q_l + N;
    ushort* v_l   = q_r + N;                        // plane layout
    ushort* v_r   = v_l + N;                        // plane layout
    ushort* f_r2l = v_r + N;
    ushort* f_l2r = f_r2l + N;

    dim3 blk(256);
    dim3 g_c1(512);            // B*HW/256
    dim3 g_dw(4, 256, 2);      // wtile, h, b
    dim3 g_att(512);           // b*h
    dim3 g_p3(2048);           // B*HW/64
    dim3 g_p4(2048);           // (b*64+c)*16 + htile

    wtrans_k<<<6, blk, 0, stream>>>(lp1_w1, rp1_w1, lp2_w1, rp2_w1, lp3_w, rp3_w, wT);

    conv1x1_k<<<g_c1, blk, 0, stream>>>(x_l, wT + 0 * 4096, lp1_b1, tmp);
    dw3x3_t_k<<<g_dw, blk, 0, stream>>>(tmp, lp1_w2, lp1_b2, q_l, 0);
    conv1x1_k<<<g_c1, blk, 0, stream>>>(x_r, wT + 1 * 4096, rp1_b1, tmp);
    dw3x3_t_k<<<g_dw, blk, 0, stream>>>(tmp, rp1_w2, rp1_b2, q_r, 0);
    conv1x1_k<<<g_c1, blk, 0, stream>>>(x_l, wT + 2 * 4096, lp2_b1, tmp);
    dw3x3_t_k<<<g_dw, blk, 0, stream>>>(tmp, lp2_w2, lp2_b2, v_l, 2);
    conv1x1_k<<<g_c1, blk, 0, stream>>>(x_r, wT + 3 * 4096, rp2_b1, tmp);
    dw3x3_t_k<<<g_dw, blk, 0, stream>>>(tmp, rp2_w2, rp2_b2, v_r, 2);

    att2_k<<<g_att, blk, 0, stream>>>(q_l, q_r, v_l, v_r, f_r2l, f_l2r);

    p3_k<<<g_p3, blk, 0, stream>>>(f_r2l, f_l2r, wT + 4 * 4096, lp3_b, wT + 5 * 4096, rp3_b, tmp);

    p4_k<<<g_p4, blk, 0, stream>>>(x_l, x_r, tmp, pa_w, pa_b, (float*)d_out);
}

// Round 4
// 503.367 us; speedup vs baseline: 1.9049x; 1.3658x over previous
//
#include <hip/hip_runtime.h>

typedef unsigned int uint;
typedef unsigned short ushort;
typedef _Float16 h2 __attribute__((ext_vector_type(2)));
typedef _Float16 f16x8 __attribute__((ext_vector_type(8)));
typedef float f32x4 __attribute__((ext_vector_type(4)));

#define HW 65536
#define W_ 256
#define H_ 256
#define C_ 64

__device__ __forceinline__ ushort f2hu(float f) { union { ushort u; _Float16 h; } x; x.h = (_Float16)f; return x.u; }
__device__ __forceinline__ float hu2f(ushort u) { union { ushort u; _Float16 h; } x; x.u = u; return (float)x.h; }

#define MFMA16(a, b, c) __builtin_amdgcn_mfma_f32_16x16x32_f16((a), (b), (c), 0, 0, 0)

// ---------------- convert 6 weight matrices (4096 fp32 each) to f16, same [o][c] layout ----------------
__global__ __launch_bounds__(256) void wconv_k(const float* __restrict__ a0, const float* __restrict__ a1,
                                               const float* __restrict__ a2, const float* __restrict__ a3,
                                               const float* __restrict__ a4, const float* __restrict__ a5,
                                               ushort* __restrict__ dst) {
    int m = blockIdx.x;
    const float* src = m == 0 ? a0 : m == 1 ? a1 : m == 2 ? a2 : m == 3 ? a3 : m == 4 ? a4 : a5;
    ushort* d = dst + m * 4096;
    for (int i = threadIdx.x; i < 4096; i += 256) d[i] = f2hu(src[i]);
}

// ---------------- conv1x1 via MFMA: y[b,o,hw] = W[o,c] x[b,c,hw] + bias[o], f16 NCHW out ----------------
// Block = 256 pixels. A-frag gathered from NCHW fp32; B-frag = wf16[o][c] b128.
// C layout: row(=pixel)=quad*4+r, col(=o)=l15. Epilogue: LDS transpose -> coalesced stores.
__global__ __launch_bounds__(256, 2) void c1_k(const float* __restrict__ x,
                                               const ushort* __restrict__ wf,
                                               const float* __restrict__ bias,
                                               ushort* __restrict__ y) {
    __shared__ ushort sY[64 * 264];     // [o][pix], stride 264
    int tid = threadIdx.x;
    int wv = tid >> 6, lane = tid & 63;
    int l15 = lane & 15, quad = lane >> 4;
    int pix0 = blockIdx.x * 256;
    int b = pix0 >> 16, hw0 = pix0 & 65535;
    const float* xb = x + ((size_t)b << 22) + hw0;

    // A-frags: pixels p = wv*64 + mt*16 + l15, k = c = kc*32 + quad*8 + j
    f16x8 aX[4][2];
#pragma unroll
    for (int mt = 0; mt < 4; ++mt) {
        int pixl = wv * 64 + mt * 16 + l15;
#pragma unroll
        for (int kc = 0; kc < 2; ++kc) {
            f16x8 a;
#pragma unroll
            for (int j = 0; j < 8; ++j) {
                int c = kc * 32 + quad * 8 + j;
                a[j] = (_Float16)xb[((size_t)c << 16) + pixl];
            }
            aX[mt][kc] = a;
        }
    }
    // B-frags: n = o = nt*16 + l15, k = c = kc*32 + quad*8 + j  -> wf[o*64 + c], contiguous 8
    f16x8 bW[4][2];
#pragma unroll
    for (int nt = 0; nt < 4; ++nt)
#pragma unroll
        for (int kc = 0; kc < 2; ++kc)
            bW[nt][kc] = *(const f16x8*)(wf + (nt * 16 + l15) * 64 + kc * 32 + quad * 8);

    f32x4 acc[4][4];
#pragma unroll
    for (int mt = 0; mt < 4; ++mt)
#pragma unroll
        for (int nt = 0; nt < 4; ++nt) {
            f32x4 s = (f32x4)(0.0f);
            s = MFMA16(aX[mt][0], bW[nt][0], s);
            s = MFMA16(aX[mt][1], bW[nt][1], s);
            acc[mt][nt] = s;
        }

    // epilogue: add bias, write to LDS [o][pix]
#pragma unroll
    for (int nt = 0; nt < 4; ++nt) {
        int o = nt * 16 + l15;
        float bv = bias[o];
#pragma unroll
        for (int mt = 0; mt < 4; ++mt) {
            int pixl = wv * 64 + mt * 16 + quad * 4;
#pragma unroll
            for (int r = 0; r < 4; r += 2) {
                h2 hh;
                hh.x = (_Float16)(acc[mt][nt][r] + bv);
                hh.y = (_Float16)(acc[mt][nt][r + 1] + bv);
                *(h2*)&sY[o * 264 + pixl + r] = hh;
            }
        }
    }
    __syncthreads();
    // coalesced stores: wave wv handles o rows wv*16..wv*16+15; lane covers 4 pixels
    ushort* yb = y + ((size_t)b << 22) + hw0;
#pragma unroll
    for (int i = 0; i < 16; ++i) {
        int o = wv * 16 + i;
        uint2 v = *(const uint2*)&sY[o * 264 + lane * 4];
        *(uint2*)(yb + ((size_t)o << 16) + lane * 4) = v;
    }
}

// ------- depthwise 3x3 (zero pad) + bias, NCHW f16 in -> f16 out -------
// mode==0: out[bh*16384 + w*64 + c]   (channels-last, for Q)
// mode==2: out[bh*16384 + c*256 + w]  (plane layout, for V)
__global__ __launch_bounds__(256) void dw3x3_t_k(const ushort* __restrict__ x,
                                                 const float* __restrict__ wgt,
                                                 const float* __restrict__ bias,
                                                 ushort* __restrict__ out,
                                                 int mode) {
    int wt = blockIdx.x;   // 0..3 (w tile of 64)
    int h  = blockIdx.y;   // 0..255
    int b  = blockIdx.z;   // 0..1
    int tid = threadIdx.x;
    int wl = tid & 63, cg = tid >> 6;
    int w0 = wt * 64;
    __shared__ float tile[64][65];   // [w][c]

    for (int i = 0; i < 16; ++i) {
        int c = i * 4 + cg;
        const float* wp = wgt + c * 9;
        float acc = bias[c];
        const ushort* xp = x + (((size_t)b * 64 + c) << 16);
#pragma unroll
        for (int dy = -1; dy <= 1; ++dy) {
            int hh = h + dy;
            if (hh < 0 || hh >= H_) continue;
            const ushort* row = xp + hh * W_;
#pragma unroll
            for (int dx = -1; dx <= 1; ++dx) {
                int ww = w0 + wl + dx;
                if (ww < 0 || ww >= W_) continue;
                acc += wp[(dy + 1) * 3 + (dx + 1)] * hu2f(row[ww]);
            }
        }
        tile[wl][c] = acc;
    }
    __syncthreads();
    size_t bh16 = ((size_t)b * H_ + h) * (size_t)(W_ * 64);
    if (mode == 0) {
        uint4* og = (uint4*)(out + bh16 + (size_t)w0 * 64);
#pragma unroll
        for (int u = 0; u < 2; ++u) {
            int i0 = (u * 256 + tid) * 8;
            ushort vals[8];
#pragma unroll
            for (int k = 0; k < 8; ++k) {
                int i = i0 + k;
                vals[k] = f2hu(tile[i >> 6][i & 63]);
            }
            uint4 o;
            o.x = (uint)vals[0] | ((uint)vals[1] << 16);
            o.y = (uint)vals[2] | ((uint)vals[3] << 16);
            o.z = (uint)vals[4] | ((uint)vals[5] << 16);
            o.w = (uint)vals[6] | ((uint)vals[7] << 16);
            og[u * 256 + tid] = o;
        }
    } else {
#pragma unroll
        for (int u = 0; u < 2; ++u) {
            int i = u * 256 + tid;           // 0..511 uint4 index
            int c = i >> 3, wch = i & 7;
            ushort vals[8];
#pragma unroll
            for (int k = 0; k < 8; ++k) vals[k] = f2hu(tile[wch * 8 + k][c]);
            uint4 o;
            o.x = (uint)vals[0] | ((uint)vals[1] << 16);
            o.y = (uint)vals[2] | ((uint)vals[3] << 16);
            o.z = (uint)vals[4] | ((uint)vals[5] << 16);
            o.w = (uint)vals[6] | ((uint)vals[7] << 16);
            *(uint4*)(out + bh16 + (size_t)c * 256 + w0 + wch * 8) = o;
        }
    }
}

// ---------------- combined MFMA attention (unchanged, verified) ----------------
__global__ __launch_bounds__(256, 2) void att2_k(const ushort* __restrict__ Ql,
                                                 const ushort* __restrict__ Qr,
                                                 const ushort* __restrict__ Vl,
                                                 const ushort* __restrict__ Vr,
                                                 ushort* __restrict__ Fr2l,
                                                 ushort* __restrict__ Fl2r) {
    int bh = blockIdx.x;
    int tid = threadIdx.x;
    int wv = tid >> 6, lane = tid & 63;
    int l15 = lane & 15, quad = lane >> 4;
    __shared__ ushort sE[256 * 72];    // E row-major [p][kcol], stride 72
    __shared__ ushort sEt[64 * 264];   // E col-major [kcol][p], stride 264

    const ushort* qlb = Ql + (size_t)bh * 16384;
    const ushort* qrb = Qr + (size_t)bh * 16384;
    const ushort* vlb = Vl + (size_t)bh * 16384;
    const ushort* vrb = Vr + (size_t)bh * 16384;
    int p0 = wv * 64;
    int c0 = wv * 16;

    f16x8 aQ[4][2];
#pragma unroll
    for (int mt = 0; mt < 4; ++mt)
#pragma unroll
        for (int kc = 0; kc < 2; ++kc)
            aQ[mt][kc] = *(const f16x8*)(qlb + (p0 + mt * 16 + l15) * 64 + kc * 32 + quad * 8);

    f16x8 onesf;
#pragma unroll
    for (int i = 0; i < 8; ++i) onesf[i] = (_Float16)1.0f;

    f32x4 num1[4][4];
    f32x4 den[4];
#pragma unroll
    for (int mt = 0; mt < 4; ++mt) {
        den[mt] = (f32x4)(0.0f);
#pragma unroll
        for (int nt = 0; nt < 4; ++nt) num1[mt][nt] = (f32x4)(0.0f);
    }

    for (int kt = 0; kt < 4; ++kt) {
        int k0 = kt * 64;
        f32x4 S[4][4];
#pragma unroll
        for (int nt = 0; nt < 4; ++nt) {
            f16x8 bQ[2];
#pragma unroll
            for (int kc = 0; kc < 2; ++kc)
                bQ[kc] = *(const f16x8*)(qrb + (k0 + nt * 16 + l15) * 64 + kc * 32 + quad * 8);
#pragma unroll
            for (int mt = 0; mt < 4; ++mt) {
                f32x4 s = (f32x4)(0.0f);
                s = MFMA16(aQ[mt][0], bQ[0], s);
                s = MFMA16(aQ[mt][1], bQ[1], s);
                S[mt][nt] = s;
            }
        }
#pragma unroll
        for (int mt = 0; mt < 4; ++mt)
#pragma unroll
            for (int nt = 0; nt < 4; ++nt)
#pragma unroll
                for (int r = 0; r < 4; ++r)
                    S[mt][nt][r] = __expf(S[mt][nt][r] * 0.125f);

        __syncthreads();
#pragma unroll
        for (int mt = 0; mt < 4; ++mt)
#pragma unroll
            for (int nt = 0; nt < 4; ++nt)
#pragma unroll
                for (int r = 0; r < 4; ++r)
                    sE[(p0 + mt * 16 + quad * 4 + r) * 72 + nt * 16 + l15] = f2hu(S[mt][nt][r]);
#pragma unroll
        for (int mt = 0; mt < 4; ++mt)
#pragma unroll
            for (int nt = 0; nt < 4; ++nt)
#pragma unroll
            for (int pr = 0; pr < 4; pr += 2) {
                h2 hh;
                hh.x = (_Float16)S[mt][nt][pr];
                hh.y = (_Float16)S[mt][nt][pr + 1];
                *(h2*)&sEt[(nt * 16 + l15) * 264 + p0 + mt * 16 + quad * 4 + pr] = hh;
            }
        __syncthreads();

        f16x8 aE[4][2];
#pragma unroll
        for (int mt = 0; mt < 4; ++mt)
#pragma unroll
            for (int kc = 0; kc < 2; ++kc)
                aE[mt][kc] = *(const f16x8*)&sE[(p0 + mt * 16 + l15) * 72 + kc * 32 + quad * 8];
#pragma unroll
        for (int mt = 0; mt < 4; ++mt) {
            den[mt] = MFMA16(aE[mt][0], onesf, den[mt]);
            den[mt] = MFMA16(aE[mt][1], onesf, den[mt]);
        }
#pragma unroll
        for (int nt = 0; nt < 4; ++nt) {
            f16x8 bV[2];
#pragma unroll
            for (int kc = 0; kc < 2; ++kc)
                bV[kc] = *(const f16x8*)(vrb + (nt * 16 + l15) * 256 + k0 + kc * 32 + quad * 8);
#pragma unroll
            for (int mt = 0; mt < 4; ++mt) {
                num1[mt][nt] = MFMA16(aE[mt][0], bV[0], num1[mt][nt]);
                num1[mt][nt] = MFMA16(aE[mt][1], bV[1], num1[mt][nt]);
            }
        }
        f32x4 num2[4], den2[4];
#pragma unroll
        for (int mt = 0; mt < 4; ++mt) { num2[mt] = (f32x4)(0.0f); den2[mt] = (f32x4)(0.0f); }
        for (int pc = 0; pc < 8; ++pc) {
            f16x8 bL = *(const f16x8*)(vlb + (c0 + l15) * 256 + pc * 32 + quad * 8);
#pragma unroll
            for (int mt = 0; mt < 4; ++mt) {
                f16x8 aT = *(const f16x8*)&sEt[(mt * 16 + l15) * 264 + pc * 32 + quad * 8];
                num2[mt] = MFMA16(aT, bL, num2[mt]);
                den2[mt] = MFMA16(aT, onesf, den2[mt]);
            }
        }
#pragma unroll
        for (int mt = 0; mt < 4; ++mt)
#pragma unroll
            for (int r = 0; r < 4; ++r) {
                float v = num2[mt][r] * (1.0f / den2[mt][r]);
                Fl2r[(size_t)bh * 16384 + (k0 + mt * 16 + quad * 4 + r) * 64 + c0 + l15] = f2hu(v);
            }
    }
#pragma unroll
    for (int mt = 0; mt < 4; ++mt)
#pragma unroll
        for (int r = 0; r < 4; ++r) {
            float inv = 1.0f / den[mt][r];
#pragma unroll
            for (int nt = 0; nt < 4; ++nt) {
                float v = num1[mt][nt][r] * inv;
                Fr2l[(size_t)bh * 16384 + (p0 + mt * 16 + quad * 4 + r) * 64 + nt * 16 + l15] = f2hu(v);
            }
        }
}

// ------- pattn1 = lp3(F_r2l) + rp3(F_l2r) via MFMA; channels-last f16 in, NCHW f16 out -------
__global__ __launch_bounds__(256, 2) void p3m_k(const ushort* __restrict__ F1,
                                                const ushort* __restrict__ F2,
                                                const ushort* __restrict__ wf1,
                                                const float* __restrict__ b1,
                                                const ushort* __restrict__ wf2,
                                                const float* __restrict__ b2,
                                                ushort* __restrict__ outp) {
    __shared__ ushort sY[64 * 264];
    int tid = threadIdx.x;
    int wv = tid >> 6, lane = tid & 63;
    int l15 = lane & 15, quad = lane >> 4;
    int pix0 = blockIdx.x * 256;
    int b = pix0 >> 16, hw0 = pix0 & 65535;

    f32x4 acc[4][4];
#pragma unroll
    for (int mt = 0; mt < 4; ++mt)
#pragma unroll
        for (int nt = 0; nt < 4; ++nt) acc[mt][nt] = (f32x4)(0.0f);

    for (int mat = 0; mat < 2; ++mat) {
        const ushort* F = mat == 0 ? F1 : F2;
        const ushort* wf = mat == 0 ? wf1 : wf2;
        f16x8 aF[4][2], bW[4][2];
#pragma unroll
        for (int mt = 0; mt < 4; ++mt) {
            int pixg = pix0 + wv * 64 + mt * 16 + l15;
#pragma unroll
            for (int kc = 0; kc < 2; ++kc)
                aF[mt][kc] = *(const f16x8*)(F + (size_t)pixg * 64 + kc * 32 + quad * 8);
        }
#pragma unroll
        for (int nt = 0; nt < 4; ++nt)
#pragma unroll
            for (int kc = 0; kc < 2; ++kc)
                bW[nt][kc] = *(const f16x8*)(wf + (nt * 16 + l15) * 64 + kc * 32 + quad * 8);
#pragma unroll
        for (int mt = 0; mt < 4; ++mt)
#pragma unroll
            for (int nt = 0; nt < 4; ++nt) {
                acc[mt][nt] = MFMA16(aF[mt][0], bW[nt][0], acc[mt][nt]);
                acc[mt][nt] = MFMA16(aF[mt][1], bW[nt][1], acc[mt][nt]);
            }
    }

#pragma unroll
    for (int nt = 0; nt < 4; ++nt) {
        int o = nt * 16 + l15;
        float bv = b1[o] + b2[o];
#pragma unroll
        for (int mt = 0; mt < 4; ++mt) {
            int pixl = wv * 64 + mt * 16 + quad * 4;
#pragma unroll
            for (int r = 0; r < 4; r += 2) {
                h2 hh;
                hh.x = (_Float16)(acc[mt][nt][r] + bv);
                hh.y = (_Float16)(acc[mt][nt][r + 1] + bv);
                *(h2*)&sY[o * 264 + pixl + r] = hh;
            }
        }
    }
    __syncthreads();
    ushort* yb = outp + ((size_t)b << 22) + hw0;
#pragma unroll
    for (int i = 0; i < 16; ++i) {
        int o = wv * 16 + i;
        uint2 v = *(const uint2*)&sY[o * 264 + lane * 4];
        *(uint2*)(yb + ((size_t)o << 16) + lane * 4) = v;
    }
}

// ------- pixel attention 7x7 reflect + double sigmoid + blend, LDS-tiled -------
__global__ __launch_bounds__(256) void p4_k(const float* __restrict__ x_l,
                                            const float* __restrict__ x_r,
                                            const ushort* __restrict__ pt,
                                            const float* __restrict__ pw,
                                            const float* __restrict__ pb,
                                            float* __restrict__ out) {
    __shared__ float s_t[22 * 264];
    __shared__ float p_t[22 * 264];
    int tid = threadIdx.x;
    int tile = blockIdx.x & 15;
    int bc = blockIdx.x >> 4;        // b*64 + c
    int c = bc & 63;
    int h0 = tile << 4;
    size_t cbase = (size_t)bc << 16;

    for (int r = 0; r < 22; ++r) {
        int hh = h0 + r - 3;
        hh = hh < 0 ? -hh : (hh > 255 ? 510 - hh : hh);
        size_t rb = cbase + (size_t)hh * 256;
        s_t[r * 264 + 3 + tid] = x_l[rb + tid] + x_r[rb + tid];
        p_t[r * 264 + 3 + tid] = hu2f(pt[rb + tid]);
    }
    if (tid < 132) {
        int r = tid / 6, d6 = tid % 6;
        int d   = d6 < 3 ? d6 : 256 + d6;
        int src = d6 < 3 ? (3 - d6) : (257 - d6);
        int hh = h0 + r - 3;
        hh = hh < 0 ? -hh : (hh > 255 ? 510 - hh : hh);
        size_t rb = cbase + (size_t)hh * 256;
        s_t[r * 264 + d] = x_l[rb + src] + x_r[rb + src];
        p_t[r * 264 + d] = hu2f(pt[rb + src]);
    }
    __syncthreads();

    const float* wAp = pw + c * 98;
    const float* wBp = wAp + 49;
    float bias = pb[c];
    int w = tid;
    float a0 = bias, a1 = bias, a2 = bias, a3 = bias, a4 = bias, a5 = bias, a6 = bias;
    size_t obase = cbase + (size_t)h0 * 256 + w;

#pragma unroll
    for (int r = 0; r < 22; ++r) {
#pragma unroll
        for (int j = 0; j < 7; ++j) {
            float sv = s_t[r * 264 + w + j];
            float pv = p_t[r * 264 + w + j];
            a0 += wAp[42 + j] * sv + wBp[42 + j] * pv;
            a1 += wAp[35 + j] * sv + wBp[35 + j] * pv;
            a2 += wAp[28 + j] * sv + wBp[28 + j] * pv;
            a3 += wAp[21 + j] * sv + wBp[21 + j] * pv;
            a4 += wAp[14 + j] * sv + wBp[14 + j] * pv;
            a5 += wAp[ 7 + j] * sv + wBp[ 7 + j] * pv;
            a6 += wAp[     j] * sv + wBp[     j] * pv;
        }
        if (r >= 6) {
            int o = r - 6;
            size_t idx = obase + (size_t)o * 256;
            float xl = x_l[idx], xr = x_r[idx];
            float s1 = 1.0f / (1.0f + __expf(-a0));
            float a  = 1.0f / (1.0f + __expf(-s1));
            out[idx] = xr + a * (xl - xr);
        }
        a0 = a1; a1 = a2; a2 = a3; a3 = a4; a4 = a5; a5 = a6; a6 = bias;
    }
}

extern "C" void kernel_launch(void* const* d_in, const int* in_sizes, int n_in,
                              void* d_out, int out_size, void* d_ws, size_t ws_size,
                              hipStream_t stream) {
    const float* x_l = (const float*)d_in[0];
    const float* x_r = (const float*)d_in[1];
    const float* lp1_w1 = (const float*)d_in[2];
    const float* lp1_b1 = (const float*)d_in[3];
    const float* lp1_w2 = (const float*)d_in[4];
    const float* lp1_b2 = (const float*)d_in[5];
    const float* rp1_w1 = (const float*)d_in[6];
    const float* rp1_b1 = (const float*)d_in[7];
    const float* rp1_w2 = (const float*)d_in[8];
    const float* rp1_b2 = (const float*)d_in[9];
    const float* lp2_w1 = (const float*)d_in[10];
    const float* lp2_b1 = (const float*)d_in[11];
    const float* lp2_w2 = (const float*)d_in[12];
    const float* lp2_b2 = (const float*)d_in[13];
    const float* rp2_w1 = (const float*)d_in[14];
    const float* rp2_b1 = (const float*)d_in[15];
    const float* rp2_w2 = (const float*)d_in[16];
    const float* rp2_b2 = (const float*)d_in[17];
    const float* lp3_w = (const float*)d_in[18];
    const float* lp3_b = (const float*)d_in[19];
    const float* rp3_w = (const float*)d_in[20];
    const float* rp3_b = (const float*)d_in[21];
    const float* pa_w = (const float*)d_in[22];
    const float* pa_b = (const float*)d_in[23];

    const size_t N = (size_t)2 * 64 * 256 * 256;    // 8388608
    char* ws = (char*)d_ws;
    ushort* tmp  = (ushort*)ws;                     // N u16 (conv1x1 out, later pattn1)
    ushort* wf16 = (ushort*)(ws + N * 2);           // 6 * 4096 f16 weights [o][c]
    ushort* q_l   = (ushort*)(ws + N * 4);
    ushort* q_r   = q_l + N;
    ushort* v_l   = q_r + N;                        // plane layout
    ushort* v_r   = v_l + N;                        // plane layout
    ushort* f_r2l = v_r + N;
    ushort* f_l2r = f_r2l + N;

    dim3 blk(256);
    dim3 g_c1(512);            // B*HW/256
    dim3 g_dw(4, 256, 2);      // wtile, h, b
    dim3 g_att(512);           // b*h
    dim3 g_p3(512);            // B*HW/256
    dim3 g_p4(2048);           // (b*64+c)*16 + htile

    wconv_k<<<6, blk, 0, stream>>>(lp1_w1, rp1_w1, lp2_w1, rp2_w1, lp3_w, rp3_w, wf16);

    c1_k<<<g_c1, blk, 0, stream>>>(x_l, wf16 + 0 * 4096, lp1_b1, tmp);
    dw3x3_t_k<<<g_dw, blk, 0, stream>>>(tmp, lp1_w2, lp1_b2, q_l, 0);
    c1_k<<<g_c1, blk, 0, stream>>>(x_r, wf16 + 1 * 4096, rp1_b1, tmp);
    dw3x3_t_k<<<g_dw, blk, 0, stream>>>(tmp, rp1_w2, rp1_b2, q_r, 0);
    c1_k<<<g_c1, blk, 0, stream>>>(x_l, wf16 + 2 * 4096, lp2_b1, tmp);
    dw3x3_t_k<<<g_dw, blk, 0, stream>>>(tmp, lp2_w2, lp2_b2, v_l, 2);
    c1_k<<<g_c1, blk, 0, stream>>>(x_r, wf16 + 3 * 4096, rp2_b1, tmp);
    dw3x3_t_k<<<g_dw, blk, 0, stream>>>(tmp, rp2_w2, rp2_b2, v_r, 2);

    att2_k<<<g_att, blk, 0, stream>>>(q_l, q_r, v_l, v_r, f_r2l, f_l2r);

    p3m_k<<<g_p3, blk, 0, stream>>>(f_r2l, f_l2r, wf16 + 4 * 4096, lp3_b, wf16 + 5 * 4096, rp3_b, tmp);

    p4_k<<<g_p4, blk, 0, stream>>>(x_l, x_r, tmp, pa_w, pa_b, (float*)d_out);
}